// Round 5
// baseline (152.234 us; speedup 1.0000x reference)
//
#include <hip/hip_runtime.h>
#include <math.h>

#define T_LEN 4096
#define C_CH  128
#define B_N   32
#define NEG   0.01f

// ---------------- Kernel 1: per-(b,c) row mean over T ----------------
__global__ __launch_bounds__(256) void row_mean_kernel(const float* __restrict__ x,
                                                       float* __restrict__ means) {
    int row = blockIdx.x;                 // b*C + c
    const float4* xr4 = (const float4*)(x + (size_t)row * T_LEN);
    int tid = threadIdx.x;
    float s = 0.f;
    #pragma unroll
    for (int i = 0; i < 4; ++i) {         // 4096/4 = 1024 float4, 256 threads
        float4 v = xr4[tid + i * 256];
        s += v.x + v.y + v.z + v.w;
    }
    #pragma unroll
    for (int off = 32; off > 0; off >>= 1) s += __shfl_down(s, off, 64);
    __shared__ float wsum[4];
    if ((tid & 63) == 0) wsum[tid >> 6] = s;
    __syncthreads();
    if (tid == 0) {
        means[row] = (wsum[0] + wsum[1] + wsum[2] + wsum[3]) * (1.0f / T_LEN);
    }
}

// ---------------- Kernel 2: fused features + depthwise conv + epilogue ----------------
// Block: 256 threads. lane c = c0 + (tid&63); t-group th = tid>>6 (4 groups of LT=16).
// Each thread: 1 channel, 16 consecutive t outputs.
#define LT 16
#define TT 64   // t per block = 4*LT

__global__ __launch_bounds__(256) void fused_kernel(const float* __restrict__ x,
                                                    const float* __restrict__ w,
                                                    const float* __restrict__ bias,
                                                    const float* __restrict__ means,
                                                    float* __restrict__ out) {
    const int b    = blockIdx.z;
    const int cblk = blockIdx.y;          // 0..1
    const int tblk = blockIdx.x;          // 0..63
    const int tid  = threadIdx.x;
    const int c    = cblk * 64 + (tid & 63);
    const int th   = tid >> 6;
    const int ts   = tblk * TT + th * LT;

    const float* xr = x + ((size_t)(b * C_CH + c)) * T_LEN;
    const float  mean = means[b * C_CH + c];
    const float  bs   = bias[c];

    // depthwise weights for this channel: w[c][h][k], h=0..5, k=0..4
    float wv[30];
    #pragma unroll
    for (int i = 0; i < 30; ++i) wv[i] = w[c * 30 + i];

    // Load x[ts-8 .. ts+24) -> 32 floats (16B-aligned since ts%16==0).
    // Needed range is [ts-4, ts+LT+3]; padded for alignment.
    float va[32];
    const int gbase = ts - 8;
    if (gbase >= 0 && gbase + 32 <= T_LEN) {
        const float4* p = (const float4*)(xr + gbase);
        #pragma unroll
        for (int i = 0; i < 8; ++i) {
            float4 v = p[i];
            va[4*i+0] = v.x; va[4*i+1] = v.y; va[4*i+2] = v.z; va[4*i+3] = v.w;
        }
    } else {
        #pragma unroll
        for (int i = 0; i < 32; ++i) {
            int g = gbase + i;
            va[i] = (g >= 0 && g < T_LEN) ? xr[g] : 0.f;
        }
    }

    float acc[LT];
    #pragma unroll
    for (int i = 0; i < LT; ++i) acc[i] = 0.f;

    // Feature positions j = ts-2 .. ts+LT+1 (conv taps). Features outside [0,T) are
    // zero (conv zero-pad) -> skip. x[j+d] lives at va[(j+d) - (ts-8)] = va[lj+6+d].
    #pragma unroll
    for (int lj = 0; lj < LT + 4; ++lj) {
        const int j = ts - 2 + lj;
        if (j < 0 || j >= T_LEN) continue;          // wave-uniform

        float s = 0.f, s2 = 0.f;
        float mx = -INFINITY, mn = INFINITY;
        #pragma unroll
        for (int d = -2; d <= 2; ++d) {
            const int gk = j + d;
            if (gk >= 0 && gk < T_LEN) {            // wave-uniform
                const float v = va[lj + 6 + d];
                s  += v;
                s2 += v * v;
                mx = fmaxf(mx, v);
                mn = fminf(mn, v);
            }
        }
        const float avg = s * 0.2f;                 // zero-padded avg: always /5
        const float var = fmaxf(s2 * 0.2f - avg * avg, 1e-6f);
        const float sd  = sqrtf(var);
        const float xc  = va[lj + 6];
        float tm = xc - avg; tm = tm * tm * tm;

        const float F0 = xc, F1 = mean, F2 = sd, F3 = tm, F4 = mx, F5 = mn;

        // scatter into outputs t = j+dt, tap k = 2-dt
        #pragma unroll
        for (int dt = -2; dt <= 2; ++dt) {
            const int lt = lj - 2 + dt;             // compile-time after unroll
            if (lt < 0 || lt >= LT) continue;
            const int k = 2 - dt;
            acc[lt] += F0 * wv[0*5 + k] + F1 * wv[1*5 + k] + F2 * wv[2*5 + k]
                     + F3 * wv[3*5 + k] + F4 * wv[4*5 + k] + F5 * wv[5*5 + k];
        }
    }

    // epilogue: bias, leaky relu, residual, transposed store out[b][t][c]
    #pragma unroll
    for (int lt = 0; lt < LT; ++lt) {
        float o = acc[lt] + bs;
        o = (o > 0.f) ? o : NEG * o;
        const int t = ts + lt;
        out[((size_t)b * T_LEN + t) * C_CH + c] = va[lt + 8] + o;
    }
}

extern "C" void kernel_launch(void* const* d_in, const int* in_sizes, int n_in,
                              void* d_out, int out_size, void* d_ws, size_t ws_size,
                              hipStream_t stream) {
    const float* x    = (const float*)d_in[0];
    const float* w    = (const float*)d_in[1];
    const float* bias = (const float*)d_in[2];
    float* means = (float*)d_ws;                    // 4096 floats
    float* out   = (float*)d_out;

    row_mean_kernel<<<dim3(B_N * C_CH), dim3(256), 0, stream>>>(x, means);
    fused_kernel<<<dim3(T_LEN / TT, C_CH / 64, B_N), dim3(256), 0, stream>>>(x, w, bias, means, out);
}

// Round 9
// 138.969 us; speedup vs baseline: 1.0955x; 1.0955x over previous
//
#include <hip/hip_runtime.h>
#include <math.h>

#define T_LEN 4096
#define C_CH  128
#define B_N   32

// ---------------- Kernel 1: per-(b,c) row mean, one wave per row ----------------
__global__ __launch_bounds__(256) void row_mean_kernel(const float* __restrict__ x,
                                                       float* __restrict__ means) {
    const int wid  = ((blockIdx.x << 8) + threadIdx.x) >> 6;   // global wave id = row
    const int lane = threadIdx.x & 63;
    const float4* r = (const float4*)(x + ((size_t)wid << 12)); // row base (4096 floats)
    float s = 0.f;
    #pragma unroll
    for (int i = 0; i < 16; ++i) {                              // 64 lanes * 16 float4 = 4096
        float4 v = r[lane + (i << 6)];
        s += (v.x + v.y) + (v.z + v.w);
    }
    #pragma unroll
    for (int off = 32; off > 0; off >>= 1) s += __shfl_down(s, off, 64);
    if (lane == 0) means[wid] = s * (1.0f / T_LEN);
}

// ---------------- Kernel 2: fused features + depthwise conv + epilogue ----------------
// Block: 256 threads = 64 channels (lane) x 4 t-groups (th). Each thread: 1 channel, 16 t.
#define LT 16
#define TT 64

__global__ __launch_bounds__(256, 4) void fused_kernel(const float* __restrict__ x,
                                                       const float* __restrict__ w,
                                                       const float* __restrict__ bias,
                                                       const float* __restrict__ means,
                                                       float* __restrict__ out) {
    const int b    = blockIdx.z;
    const int cblk = blockIdx.y;
    const int tblk = blockIdx.x;
    const int tid  = threadIdx.x;
    const int c    = cblk * 64 + (tid & 63);
    const int th   = tid >> 6;
    const int ts   = tblk * TT + th * LT;

    const float* xr  = x + ((size_t)(b * C_CH + c)) * T_LEN;
    const float mean = means[b * C_CH + c];
    const float bs   = bias[c];

    // weights w[c][h][k] as 15 float2 (c*30 floats = 8B aligned)
    float2 wv2[15];
    const float2* pw2 = (const float2*)(w + c * 30);
    #pragma unroll
    for (int i = 0; i < 15; ++i) wv2[i] = pw2[i];
    // compile-time index accessor
    #define W(idx) (((idx) & 1) ? wv2[(idx) >> 1].y : wv2[(idx) >> 1].x)

    const int gbase = ts - 8;
    float* po = out + ((size_t)(b * T_LEN + ts)) * C_CH + c;

    if (gbase >= 0 && gbase + 32 <= T_LEN) {
        // ---------- interior fast path: completely branch-free ----------
        float va[32];
        const float4* p = (const float4*)(xr + gbase);
        #pragma unroll
        for (int i = 0; i < 8; ++i) {
            float4 v = p[i];
            va[4*i+0] = v.x; va[4*i+1] = v.y; va[4*i+2] = v.z; va[4*i+3] = v.w;
        }

        // g_mean feature is constant over all taps: fold mean * sum(w[1][:]) + bias into acc init
        const float w1s = ((W(5) + W(6)) + (W(7) + W(8))) + W(9);
        float acc[LT];
        #pragma unroll
        for (int i = 0; i < LT; ++i) acc[i] = fmaf(mean, w1s, bs);

        #pragma unroll
        for (int lj = 0; lj < LT + 4; ++lj) {       // feature positions j = ts-2+lj
            const float v0 = va[lj+4], v1 = va[lj+5], v2 = va[lj+6], v3 = va[lj+7], v4 = va[lj+8];
            const float s  = ((v0 + v1) + (v2 + v3)) + v4;
            float s2 = v0 * v0;
            s2 = fmaf(v1, v1, s2); s2 = fmaf(v2, v2, s2);
            s2 = fmaf(v3, v3, s2); s2 = fmaf(v4, v4, s2);
            const float mx = fmaxf(fmaxf(fmaxf(v0, v1), fmaxf(v2, v3)), v4);
            const float mn = fminf(fminf(fminf(v0, v1), fminf(v2, v3)), v4);
            const float avg = s * 0.2f;
            float var = fmaf(-avg, avg, s2 * 0.2f);
            var = fmaxf(var, 1e-6f);
            const float sd = __builtin_amdgcn_sqrtf(var);
            const float dm = v2 - avg;
            const float tm = dm * dm * dm;

            #pragma unroll
            for (int dt = -2; dt <= 2; ++dt) {
                const int lt = lj - 2 + dt;          // compile-time after unroll
                if (lt < 0 || lt >= LT) continue;
                const int k = 2 - dt;
                float a = acc[lt];
                a = fmaf(v2, W(k),      a);          // x
                a = fmaf(sd, W(10 + k), a);          // rolling_std
                a = fmaf(tm, W(15 + k), a);          // third moment
                a = fmaf(mx, W(20 + k), a);          // rolling_max
                a = fmaf(mn, W(25 + k), a);          // rolling_min
                acc[lt] = a;
            }
        }

        #pragma unroll
        for (int lt = 0; lt < LT; ++lt) {
            float o = acc[lt];
            o = fmaxf(o, 0.01f * o);                 // leaky relu
            po[lt * C_CH] = va[lt + 8] + o;          // residual + transposed store
        }
    } else {
        // ---------- edge path (ts==0 or ts==4080 only): fully guarded ----------
        float va[32];
        #pragma unroll
        for (int i = 0; i < 32; ++i) {
            int g = gbase + i;
            va[i] = (g >= 0 && g < T_LEN) ? xr[g] : 0.f;
        }
        float acc[LT];
        #pragma unroll
        for (int i = 0; i < LT; ++i) acc[i] = bs;

        #pragma unroll
        for (int lj = 0; lj < LT + 4; ++lj) {
            const int j = ts - 2 + lj;
            if (j < 0 || j >= T_LEN) continue;       // feature zero outside [0,T)
            float s = 0.f, s2 = 0.f, mx = -INFINITY, mn = INFINITY;
            #pragma unroll
            for (int d = -2; d <= 2; ++d) {
                int gk = j + d;
                if (gk >= 0 && gk < T_LEN) {
                    float v = va[lj + 6 + d];
                    s += v; s2 = fmaf(v, v, s2);
                    mx = fmaxf(mx, v); mn = fminf(mn, v);
                }
            }
            const float avg = s * 0.2f;              // zero-padded avg: always /5
            float var = fmaf(-avg, avg, s2 * 0.2f);
            var = fmaxf(var, 1e-6f);
            const float sd = __builtin_amdgcn_sqrtf(var);
            const float xc = va[lj + 6];
            const float dm = xc - avg;
            const float tm = dm * dm * dm;

            #pragma unroll
            for (int dt = -2; dt <= 2; ++dt) {
                const int lt = lj - 2 + dt;
                if (lt < 0 || lt >= LT) continue;
                const int k = 2 - dt;
                float a = acc[lt];
                a = fmaf(xc,   W(k),      a);
                a = fmaf(mean, W(5 + k),  a);
                a = fmaf(sd,   W(10 + k), a);
                a = fmaf(tm,   W(15 + k), a);
                a = fmaf(mx,   W(20 + k), a);
                a = fmaf(mn,   W(25 + k), a);
                acc[lt] = a;
            }
        }

        #pragma unroll
        for (int lt = 0; lt < LT; ++lt) {
            float o = acc[lt];
            o = fmaxf(o, 0.01f * o);
            po[lt * C_CH] = va[lt + 8] + o;
        }
    }
    #undef W
}

extern "C" void kernel_launch(void* const* d_in, const int* in_sizes, int n_in,
                              void* d_out, int out_size, void* d_ws, size_t ws_size,
                              hipStream_t stream) {
    const float* x    = (const float*)d_in[0];
    const float* w    = (const float*)d_in[1];
    const float* bias = (const float*)d_in[2];
    float* means = (float*)d_ws;                    // 4096 floats
    float* out   = (float*)d_out;

    row_mean_kernel<<<dim3((B_N * C_CH) / 4), dim3(256), 0, stream>>>(x, means);
    fused_kernel<<<dim3(T_LEN / TT, C_CH / 64, B_N), dim3(256), 0, stream>>>(x, w, bias, means, out);
}